// Round 14
// baseline (135.843 us; speedup 1.0000x reference)
//
#include <hip/hip_runtime.h>

#define TPB 256

typedef __attribute__((ext_vector_type(8))) __bf16 bf16x8;
typedef __attribute__((ext_vector_type(4))) float f32x4;
typedef __attribute__((ext_vector_type(8))) unsigned short u16x8;
typedef __attribute__((ext_vector_type(4))) unsigned short u16x4;
typedef __attribute__((ext_vector_type(4))) unsigned int u32x4;
typedef __attribute__((ext_vector_type(2))) unsigned int u32x2;

typedef __attribute__((address_space(1))) const void gconst_void;
typedef __attribute__((address_space(3))) void lds_void;

__device__ __forceinline__ unsigned short f2bf(float f) {
  unsigned u = __builtin_bit_cast(unsigned, f);
  u += 0x7FFFu + ((u >> 16) & 1u);
  return (unsigned short)(u >> 16);
}

__device__ __forceinline__ float exp2_fast(float x) {
  float r;
  asm("v_exp_f32 %0, %1" : "=v"(r) : "v"(x));
  return r;
}

__device__ __forceinline__ float rcp_fast(float x) {
  float r;
  asm("v_rcp_f32 %0, %1" : "=v"(r) : "v"(x));
  return r;
}

__device__ __forceinline__ unsigned cvt_pk_bf16(float lo, float hi) {
  unsigned r;
  asm("v_cvt_pk_bf16_f32 %0, %1, %2" : "=v"(r) : "v"(lo), "v"(hi));
  return r;
}

// Packed fragment layout for a K-contiguous matrix X[r][k] (k:512):
//   flat_short(r,k) = (r>>4)*8192 + (k>>5)*512 + ((k>>3)&3)*128 + (r&15)*8 + (k&7)
// Packed-V (attn PV A-operand), per bh (65536 shorts), s-tile of 64:
//   V[ch][s] at stile*4096 + nj*1024 + kk*512 + g*128 + li*8 + e
//   where ch = nj*16 + li, s = kk*32 + g*8 + e.

// ---------------- Fused GroupNorm: one block per (b,g); writes hnT packed.
__global__ __launch_bounds__(256) void k_gn_fused(const float* __restrict__ x,
                                                  const float* __restrict__ nw,
                                                  const float* __restrict__ nb,
                                                  unsigned short* __restrict__ hnT) {
  int bg = blockIdx.x;
  int b = bg >> 5, g = bg & 31;
  size_t base = (size_t)(b * 512 + g * 16) * 1024;
  const float4* p = reinterpret_cast<const float4*>(x + base);
  float s = 0.f, ss = 0.f;
#pragma unroll
  for (int i = 0; i < 16; ++i) {
    float4 v = p[threadIdx.x + i * 256];
    s += v.x + v.y + v.z + v.w;
    ss += v.x * v.x + v.y * v.y + v.z * v.z + v.w * v.w;
  }
#pragma unroll
  for (int off = 1; off < 64; off <<= 1) {
    s += __shfl_xor(s, off, 64);
    ss += __shfl_xor(ss, off, 64);
  }
  __shared__ float rbuf[4][2];
  __shared__ float stat[2];
  int wave = threadIdx.x >> 6;
  if ((threadIdx.x & 63) == 0) { rbuf[wave][0] = s; rbuf[wave][1] = ss; }
  __syncthreads();
  if (threadIdx.x == 0) {
    float S = 0.f, SS = 0.f;
    for (int i = 0; i < 4; ++i) { S += rbuf[i][0]; SS += rbuf[i][1]; }
    float m = S * (1.f / 16384.f);
    float var = SS * (1.f / 16384.f) - m * m;
    stat[0] = m;
    stat[1] = rsqrtf(var + 1e-5f);
  }
  __syncthreads();
  float mu = stat[0], rinv = stat[1];

  int tid = threadIdx.x;
#pragma unroll
  for (int q = 0; q < 2; ++q) {
    int c0 = g * 16 + q * 8;
    float a[8], bb[8];
#pragma unroll
    for (int cc = 0; cc < 8; ++cc) {
      a[cc] = rinv * nw[c0 + cc];
      bb[cc] = nb[c0 + cc] - mu * a[cc];
    }
    size_t cpart = (size_t)(c0 >> 5) * 512 + (size_t)((c0 >> 3) & 3) * 128;
#pragma unroll
    for (int it = 0; it < 4; ++it) {
      int t = it * 256 + tid;
      u16x8 o;
#pragma unroll
      for (int cc = 0; cc < 8; ++cc) {
        float v = x[base + (size_t)(q * 8 + cc) * 1024 + t];
        o[cc] = f2bf(v * a[cc] + bb[cc]);
      }
      size_t dst = (size_t)b * 524288 + (size_t)(t >> 4) * 8192 + cpart + (t & 15) * 8;
      *reinterpret_cast<u16x8*>(hnT + dst) = o;
    }
  }
}

// ---------------- merged weight prep: qkv packed-frag + proj row-major bf16
__global__ void k_prep_w(const float* __restrict__ qkv_w, const float* __restrict__ proj_w,
                         unsigned short* __restrict__ wqb, unsigned short* __restrict__ wpb) {
  int i = blockIdx.x * blockDim.x + threadIdx.x;
  if (i < 98304) {
    int r = i >> 6, k8 = i & 63;
    const float4* s = reinterpret_cast<const float4*>(qkv_w + (size_t)r * 512 + k8 * 8);
    float4 v0 = s[0], v1 = s[1];
    u16x8 o;
    o[0] = f2bf(v0.x); o[1] = f2bf(v0.y); o[2] = f2bf(v0.z); o[3] = f2bf(v0.w);
    o[4] = f2bf(v1.x); o[5] = f2bf(v1.y); o[6] = f2bf(v1.z); o[7] = f2bf(v1.w);
    size_t d = (size_t)(r >> 4) * 8192 + (size_t)(k8 >> 2) * 512 + (k8 & 3) * 128 + (r & 15) * 8;
    *reinterpret_cast<u16x8*>(wqb + d) = o;
  } else {
    int j = i - 98304;  // j < 65536
    float4 v = reinterpret_cast<const float4*>(proj_w)[j];
    u16x4 o;
    o[0] = f2bf(v.x); o[1] = f2bf(v.y); o[2] = f2bf(v.z); o[3] = f2bf(v.w);
    reinterpret_cast<u16x4*>(wpb)[j] = o;
  }
}

#define MFMAS(AF, BF)                                                                     \
  do {                                                                                    \
    _Pragma("unroll") for (int mi = 0; mi < 4; ++mi)                                      \
      _Pragma("unroll") for (int ni = 0; ni < 4; ++ni)                                    \
        acc[mi][ni] =                                                                     \
            __builtin_amdgcn_mfma_f32_16x16x32_bf16(AF[mi], BF[ni], acc[mi][ni], 0, 0, 0);\
  } while (0)

#define LOADT(DA, DB, kb)                                                                 \
  do {                                                                                    \
    _Pragma("unroll") for (int mi = 0; mi < 4; ++mi)                                      \
      DA[mi] = *reinterpret_cast<const bf16x8*>(pA + (size_t)mi * 8192 + (kb) * 512);     \
    _Pragma("unroll") for (int ni = 0; ni < 4; ++ni)                                      \
      DB[ni] = *reinterpret_cast<const bf16x8*>(pB + (size_t)ni * 8192 + (kb) * 512);     \
  } while (0)

// ---------------- QKV GEMM: LDS-free packed-operand register streaming.
__global__ __launch_bounds__(256, 1) void k_qkv_gemm(
    const unsigned short* __restrict__ hnT, const unsigned short* __restrict__ wq,
    const float* __restrict__ qkv_b, unsigned short* __restrict__ Q,
    unsigned short* __restrict__ Kq, unsigned short* __restrict__ Vq) {
  int tid = threadIdx.x;
  int lane = tid & 63, wave = tid >> 6;
  int wm = wave >> 1, wn = wave & 1;
  int g = lane >> 4, li = lane & 15;

  int wg = blockIdx.x;
  int lin = (wg & 7) * 192 + (wg >> 3);
  int bx = lin % 12;
  int tmp = lin / 12;
  int by = tmp & 7;
  int b = tmp >> 3;
  int mbase = by * 128;  // t
  int nbase = bx * 128;  // o

  const unsigned short* pA =
      hnT + (size_t)b * 524288 + (size_t)((mbase + wm * 64) >> 4) * 8192 + lane * 8;
  const unsigned short* pB = wq + (size_t)((nbase + wn * 64) >> 4) * 8192 + lane * 8;

  f32x4 zero = {0.f, 0.f, 0.f, 0.f};
  f32x4 acc[4][4];
#pragma unroll
  for (int mi = 0; mi < 4; ++mi)
#pragma unroll
    for (int ni = 0; ni < 4; ++ni) acc[mi][ni] = zero;

  bf16x8 a0[4], b0[4], a1[4], b1[4];
  LOADT(a0, b0, 0);
#pragma unroll
  for (int kb = 0; kb < 16; kb += 2) {
    if (kb + 1 < 16) LOADT(a1, b1, kb + 1);
    MFMAS(a0, b0);
    if (kb + 2 < 16) LOADT(a0, b0, kb + 2);
    MFMAS(a1, b1);
  }

  // per-side scale: sqrt( (1/sqrt(ch)) * log2(e) ) -> QK^T scores in log2 domain
  const float SCALE = 0.42466090143f;
#pragma unroll
  for (int ni = 0; ni < 4; ++ni) {
    int o = nbase + wn * 64 + ni * 16 + li;
    int h = o / 192;
    int j = o - h * 192;
    int bh = b * 8 + h;
    float bias = qkv_b[o];
#pragma unroll
    for (int mi = 0; mi < 4; ++mi) {
      int t0 = mbase + wm * 64 + mi * 16 + g * 4;
      f32x4 v = acc[mi][ni];
      if (j < 64) {
#pragma unroll
        for (int r = 0; r < 4; ++r)
          Q[((size_t)bh * 1024 + t0 + r) * 64 + j] = f2bf((v[r] + bias) * SCALE);
      } else if (j < 128) {
#pragma unroll
        for (int r = 0; r < 4; ++r)
          Kq[((size_t)bh * 1024 + t0 + r) * 64 + (j - 64)] = f2bf((v[r] + bias) * SCALE);
      } else {
        int ch = j - 128;
        int nj = ch >> 4, liv = ch & 15;
        int stile = t0 >> 6, s0 = t0 & 63;
        int kkc = s0 >> 5, gk = (s0 >> 3) & 3, e0 = s0 & 7;
        u16x4 pv;
#pragma unroll
        for (int r = 0; r < 4; ++r) pv[r] = f2bf(v[r] + bias);
        *reinterpret_cast<u16x4*>(Vq + (size_t)bh * 65536 + (size_t)stile * 4096 +
                                  nj * 1024 + kkc * 512 + gk * 128 + liv * 8 + e0) = pv;
      }
    }
  }
}

// ---------------- Flash attention: 4 waves x 64 q-rows (4 q-frags, 2 q-tiles of 128),
// KVBLK=128 phases; K LDS dbuf + V reg-stream are SHARED across all 4 q-frags.
__global__ __launch_bounds__(256) void k_attn(
    const unsigned short* __restrict__ Q, const unsigned short* __restrict__ K,
    const unsigned short* __restrict__ Vp, unsigned short* __restrict__ aT) {
  __shared__ unsigned short Kls[2][8192];  // [128 rows][64 ch], XOR-swizzled
  int tid = threadIdx.x;
  int lane = tid & 63, w = tid >> 6;
  int g = lane >> 4, li = lane & 15;

  int wg = blockIdx.x;  // 512 blocks
  int lin = (wg & 7) * 64 + (wg >> 3);
  int qp = lin & 3;  // q-quarter fastest: same-XCD consecutive blocks share K/V(bh)
  int bh = lin >> 2;
  int tq0 = qp * 256;
  int b = bh >> 3, h = bh & 7;

  const unsigned short* Kg = K + (size_t)bh * 1024 * 64;
  const unsigned short* Vb = Vp + (size_t)bh * 65536 + lane * 8;

  bf16x8 qf[4][2];
#pragma unroll
  for (int qi = 0; qi < 4; ++qi) {
    int t = tq0 + (qi >> 1) * 128 + w * 32 + (qi & 1) * 16 + li;
    const unsigned short* qp_ = Q + ((size_t)bh * 1024 + t) * 64 + g * 8;
    qf[qi][0] = *reinterpret_cast<const bf16x8*>(qp_);
    qf[qi][1] = *reinterpret_cast<const bf16x8*>(qp_ + 32);
  }

  // staging: wave w stages rows [w*32, w*32+32) of the 128-row phase tile
  const unsigned short* kg[4];
#pragma unroll
  for (int i = 0; i < 4; ++i) {
    int r = w * 32 + i * 8 + (lane >> 3);
    int hh = (r ^ (r >> 2)) & 7;
    int c = ((lane & 7) ^ hh) * 8;
    kg[i] = Kg + (size_t)r * 64 + c;
  }

  int srowK = ((li >> 2) << 3) | (li & 3);

  f32x4 zero = {0.f, 0.f, 0.f, 0.f};
  f32x4 oacc[4][4];
  f32x4 l_acc[4];
#pragma unroll
  for (int qi = 0; qi < 4; ++qi) {
    l_acc[qi] = zero;
#pragma unroll
    for (int nj = 0; nj < 4; ++nj) oacc[qi][nj] = zero;
  }
  u32x4 onesw = {0x3F803F80u, 0x3F803F80u, 0x3F803F80u, 0x3F803F80u};
  bf16x8 ones = __builtin_bit_cast(bf16x8, onesw);

#define ISSUE(pp, ph)                                                                    \
  do {                                                                                   \
    _Pragma("unroll") for (int i = 0; i < 4; ++i)                                        \
        __builtin_amdgcn_global_load_lds((gconst_void*)(kg[i] + (size_t)(ph) * 8192),    \
                                         (lds_void*)&Kls[pp][w * 2048 + i * 512], 16, 0, \
                                         0);                                             \
  } while (0)

#define QK2(q0, sacc)                                                                    \
  do {                                                                                   \
    _Pragma("unroll") for (int ni = 0; ni < 4; ++ni) {                                   \
      int rK = ((ni >> 1) << 5) + ((ni & 1) << 2) + srowK;                               \
      int hs = ((rK ^ (rK >> 2)) & 7) << 4;                                              \
      int off0 = (g << 4) ^ hs;                                                          \
      int off1 = (64 + (g << 4)) ^ hs;                                                   \
      bf16x8 kf0 = *reinterpret_cast<const bf16x8*>(&kbase[rK * 64 + (off0 >> 1)]);      \
      bf16x8 kf1 = *reinterpret_cast<const bf16x8*>(&kbase[rK * 64 + (off1 >> 1)]);      \
      _Pragma("unroll") for (int u = 0; u < 2; ++u) {                                    \
        f32x4 s0 = __builtin_amdgcn_mfma_f32_16x16x32_bf16(kf0, qf[(q0) + u][0], zero, 0, 0, 0); \
        sacc[u][ni] = __builtin_amdgcn_mfma_f32_16x16x32_bf16(kf1, qf[(q0) + u][1], s0, 0, 0, 0); \
      }                                                                                  \
    }                                                                                    \
  } while (0)

#define SM2(q0, sacc)                                                                    \
  do {                                                                                   \
    _Pragma("unroll") for (int u = 0; u < 2; ++u) {                                      \
      _Pragma("unroll") for (int ni = 0; ni < 4; ++ni)                                   \
        _Pragma("unroll") for (int r = 0; r < 4; ++r)                                    \
            sacc[u][ni][r] = exp2_fast(sacc[u][ni][r]);                                  \
      _Pragma("unroll") for (int kk = 0; kk < 2; ++kk) {                                 \
        u32x4 pw;                                                                        \
        pw[0] = cvt_pk_bf16(sacc[u][2 * kk][0], sacc[u][2 * kk][1]);                     \
        pw[1] = cvt_pk_bf16(sacc[u][2 * kk][2], sacc[u][2 * kk][3]);                     \
        pw[2] = cvt_pk_bf16(sacc[u][2 * kk + 1][0], sacc[u][2 * kk + 1][1]);             \
        pw[3] = cvt_pk_bf16(sacc[u][2 * kk + 1][2], sacc[u][2 * kk + 1][3]);             \
        pfrag[(q0) + u][kk] = __builtin_bit_cast(bf16x8, pw);                            \
      }                                                                                  \
      l_acc[(q0) + u] = __builtin_amdgcn_mfma_f32_16x16x32_bf16(ones, pfrag[(q0) + u][0],\
                                                                l_acc[(q0) + u], 0, 0, 0);\
      l_acc[(q0) + u] = __builtin_amdgcn_mfma_f32_16x16x32_bf16(ones, pfrag[(q0) + u][1],\
                                                                l_acc[(q0) + u], 0, 0, 0);\
    }                                                                                    \
  } while (0)

  ISSUE(0, 0);
  for (int ph = 0; ph < 8; ++ph) {
    asm volatile("s_waitcnt vmcnt(0) lgkmcnt(0)" ::: "memory");
    __builtin_amdgcn_s_barrier();
    asm volatile("" ::: "memory");
    if (ph < 7) ISSUE((ph + 1) & 1, ph + 1);

#pragma unroll
    for (int st = 0; st < 2; ++st) {
      const unsigned short* kbase = &Kls[ph & 1][st * 4096];
      const unsigned short* vt = Vb + (size_t)(ph * 2 + st) * 4096;

      bf16x8 pfrag[4][2];

      // V nj=0,1 — latency hides under QK/SM
      bf16x8 vf0[4];
#pragma unroll
      for (int i = 0; i < 4; ++i) vf0[i] = *reinterpret_cast<const bf16x8*>(vt + i * 512);

      {
        f32x4 sacc[2][4];
        __builtin_amdgcn_s_setprio(1);
        QK2(0, sacc);
        __builtin_amdgcn_s_setprio(0);
        SM2(0, sacc);
      }
      {
        f32x4 sacc[2][4];
        __builtin_amdgcn_s_setprio(1);
        QK2(2, sacc);  // MFMA here overlaps SM2(0)'s VALU drain
        __builtin_amdgcn_s_setprio(0);
        SM2(2, sacc);
      }

      // V nj=2,3
      bf16x8 vf1[4];
#pragma unroll
      for (int i = 0; i < 4; ++i)
        vf1[i] = *reinterpret_cast<const bf16x8*>(vt + (4 + i) * 512);

      __builtin_amdgcn_s_setprio(1);
#pragma unroll
      for (int nj = 0; nj < 2; ++nj)
#pragma unroll
        for (int qi = 0; qi < 4; ++qi) {
          oacc[qi][nj] = __builtin_amdgcn_mfma_f32_16x16x32_bf16(vf0[nj * 2 + 0], pfrag[qi][0], oacc[qi][nj], 0, 0, 0);
          oacc[qi][nj] = __builtin_amdgcn_mfma_f32_16x16x32_bf16(vf0[nj * 2 + 1], pfrag[qi][1], oacc[qi][nj], 0, 0, 0);
        }
#pragma unroll
      for (int nj = 2; nj < 4; ++nj)
#pragma unroll
        for (int qi = 0; qi < 4; ++qi) {
          oacc[qi][nj] = __builtin_amdgcn_mfma_f32_16x16x32_bf16(vf1[(nj - 2) * 2 + 0], pfrag[qi][0], oacc[qi][nj], 0, 0, 0);
          oacc[qi][nj] = __builtin_amdgcn_mfma_f32_16x16x32_bf16(vf1[(nj - 2) * 2 + 1], pfrag[qi][1], oacc[qi][nj], 0, 0, 0);
        }
      __builtin_amdgcn_s_setprio(0);
    }
  }
#undef ISSUE
#undef QK2
#undef SM2

#pragma unroll
  for (int qi = 0; qi < 4; ++qi) {
    float inv = rcp_fast(l_acc[qi][0]);
    int t = tq0 + (qi >> 1) * 128 + w * 32 + (qi & 1) * 16 + li;
#pragma unroll
    for (int nj = 0; nj < 4; ++nj) {
      u32x2 ov;
      ov[0] = cvt_pk_bf16(oacc[qi][nj][0] * inv, oacc[qi][nj][1] * inv);
      ov[1] = cvt_pk_bf16(oacc[qi][nj][2] * inv, oacc[qi][nj][3] * inv);
      *reinterpret_cast<u32x2*>(aT + ((size_t)b * 1024 + t) * 512 + h * 64 + nj * 16 + g * 4) = ov;
    }
  }
}

// ---------------- proj GEMM + bias + residual: LDS 2-buffer depth-1 pipeline
__global__ __launch_bounds__(256) void k_proj_gemm(
    const unsigned short* __restrict__ aT, const unsigned short* __restrict__ wp,
    const float* __restrict__ proj_b, const float* __restrict__ x,
    float* __restrict__ out) {
  __shared__ unsigned short As[2][4096];
  __shared__ unsigned short Bs[2][4096];
  int tid = threadIdx.x;
  int lane = tid & 63, wave = tid >> 6;
  int wm = wave >> 1, wn = wave & 1;
  int g = lane >> 4, li = lane & 15;

  int wg = blockIdx.x;
  int lin = (wg & 7) * 64 + (wg >> 3);
  int bx = lin & 7;
  int tmp = lin >> 3;
  int by = tmp & 3;
  int b = tmp >> 2;
  int mbase = by * 128;  // o
  int nbase = bx * 128;  // t

  const unsigned short* Ag = wp + (size_t)mbase * 512;
  const unsigned short* Bg = aT + (size_t)b * 1024 * 512 + (size_t)nbase * 512;

  int kq = (lane & 3) ^ ((lane >> 3) & 3);
  int rst = wave * 32 + (lane >> 2);
  const char* pA0 = (const char*)Ag + (size_t)rst * 1024 + kq * 16;
  const char* pA1 = pA0 + 16 * 1024;
  const char* pB0 = (const char*)Bg + (size_t)rst * 1024 + kq * 16;
  const char* pB1 = pB0 + 16 * 1024;
  int ldsA0 = wave * 1024, ldsA1 = wave * 1024 + 512;

  int voff = 32 * li + 8 * (g ^ ((li >> 1) & 3));

  f32x4 zero = {0.f, 0.f, 0.f, 0.f};
  f32x4 acc[4][4];
#pragma unroll
  for (int mi = 0; mi < 4; ++mi)
#pragma unroll
    for (int ni = 0; ni < 4; ++ni) acc[mi][ni] = zero;

#define GISSUE(k0, buf)                                                                  \
  do {                                                                                   \
    __builtin_amdgcn_global_load_lds((gconst_void*)(pA0 + (k0) * 2),                     \
                                     (lds_void*)&As[buf][ldsA0], 16, 0, 0);              \
    __builtin_amdgcn_global_load_lds((gconst_void*)(pA1 + (k0) * 2),                     \
                                     (lds_void*)&As[buf][ldsA1], 16, 0, 0);              \
    __builtin_amdgcn_global_load_lds((gconst_void*)(pB0 + (k0) * 2),                     \
                                     (lds_void*)&Bs[buf][ldsA0], 16, 0, 0);              \
    __builtin_amdgcn_global_load_lds((gconst_void*)(pB1 + (k0) * 2),                     \
                                     (lds_void*)&Bs[buf][ldsA1], 16, 0, 0);              \
  } while (0)

  GISSUE(0, 0);
#pragma unroll
  for (int kk = 0; kk < 16; ++kk) {
    asm volatile("s_waitcnt vmcnt(0)" ::: "memory");
    __builtin_amdgcn_s_barrier();
    asm volatile("" ::: "memory");
    if (kk < 15) GISSUE((kk + 1) * 32, (kk + 1) & 1);
    const int cur = kk & 1;
    bf16x8 af[4], bfr[4];
#pragma unroll
    for (int mi = 0; mi < 4; ++mi)
      af[mi] = *reinterpret_cast<const bf16x8*>(&As[cur][wm * 2048 + mi * 512 + voff]);
#pragma unroll
    for (int ni = 0; ni < 4; ++ni)
      bfr[ni] = *reinterpret_cast<const bf16x8*>(&Bs[cur][wn * 2048 + ni * 512 + voff]);
#pragma unroll
    for (int mi = 0; mi < 4; ++mi)
#pragma unroll
      for (int ni = 0; ni < 4; ++ni)
        acc[mi][ni] = __builtin_amdgcn_mfma_f32_16x16x32_bf16(af[mi], bfr[ni], acc[mi][ni], 0, 0, 0);
  }
#undef GISSUE

#pragma unroll
  for (int mi = 0; mi < 4; ++mi) {
#pragma unroll
    for (int ni = 0; ni < 4; ++ni) {
      int t = nbase + wn * 64 + ni * 16 + li;
      f32x4 v = acc[mi][ni];
#pragma unroll
      for (int r = 0; r < 4; ++r) {
        int o = mbase + wm * 64 + mi * 16 + g * 4 + r;
        size_t idx = ((size_t)(b * 512 + o)) * 1024 + t;
        out[idx] = v[r] + proj_b[o] + x[idx];
      }
    }
  }
}

extern "C" void kernel_launch(void* const* d_in, const int* in_sizes, int n_in,
                              void* d_out, int out_size, void* d_ws, size_t ws_size,
                              hipStream_t stream) {
  (void)in_sizes; (void)n_in; (void)out_size; (void)ws_size;
  const float* x = (const float*)d_in[0];
  const float* norm_w = (const float*)d_in[1];
  const float* norm_b = (const float*)d_in[2];
  const float* qkv_w = (const float*)d_in[3];
  const float* qkv_b = (const float*)d_in[4];
  const float* proj_w = (const float*)d_in[5];
  const float* proj_b = (const float*)d_in[6];
  float* out = (float*)d_out;

  char* ws = (char*)d_ws;
  size_t off = 0;
  unsigned short* hnT = (unsigned short*)(ws + off); off += (size_t)16 * 1024 * 512 * 2;  // packed; reused as row-major aT
  unsigned short* wqb = (unsigned short*)(ws + off); off += (size_t)1536 * 512 * 2;
  unsigned short* wpb = (unsigned short*)(ws + off); off += (size_t)512 * 512 * 2;
  unsigned short* Qb = (unsigned short*)(ws + off); off += (size_t)128 * 1024 * 64 * 2;
  unsigned short* Kb = (unsigned short*)(ws + off); off += (size_t)128 * 1024 * 64 * 2;
  unsigned short* Vb = (unsigned short*)(ws + off); off += (size_t)128 * 1024 * 64 * 2;

  k_gn_fused<<<512, TPB, 0, stream>>>(x, norm_w, norm_b, hnT);
  k_prep_w<<<640, TPB, 0, stream>>>(qkv_w, proj_w, wqb, wpb);
  k_qkv_gemm<<<1536, TPB, 0, stream>>>(hnT, wqb, qkv_b, Qb, Kb, Vb);
  k_attn<<<512, TPB, 0, stream>>>(Qb, Kb, Vb, hnT /* aT, row-major */);
  k_proj_gemm<<<512, TPB, 0, stream>>>(hnT, wpb, proj_b, x, out);
}

// Round 15
// 124.811 us; speedup vs baseline: 1.0884x; 1.0884x over previous
//
#include <hip/hip_runtime.h>

#define TPB 256

typedef __attribute__((ext_vector_type(8))) __bf16 bf16x8;
typedef __attribute__((ext_vector_type(4))) float f32x4;
typedef __attribute__((ext_vector_type(8))) unsigned short u16x8;
typedef __attribute__((ext_vector_type(4))) unsigned short u16x4;
typedef __attribute__((ext_vector_type(4))) unsigned int u32x4;
typedef __attribute__((ext_vector_type(2))) unsigned int u32x2;

typedef __attribute__((address_space(1))) const void gconst_void;
typedef __attribute__((address_space(3))) void lds_void;

__device__ __forceinline__ unsigned short f2bf(float f) {
  unsigned u = __builtin_bit_cast(unsigned, f);
  u += 0x7FFFu + ((u >> 16) & 1u);
  return (unsigned short)(u >> 16);
}

__device__ __forceinline__ float exp2_fast(float x) {
  float r;
  asm("v_exp_f32 %0, %1" : "=v"(r) : "v"(x));
  return r;
}

__device__ __forceinline__ float rcp_fast(float x) {
  float r;
  asm("v_rcp_f32 %0, %1" : "=v"(r) : "v"(x));
  return r;
}

__device__ __forceinline__ unsigned cvt_pk_bf16(float lo, float hi) {
  unsigned r;
  asm("v_cvt_pk_bf16_f32 %0, %1, %2" : "=v"(r) : "v"(lo), "v"(hi));
  return r;
}

// Packed fragment layout for a K-contiguous matrix X[r][k] (k:512):
//   flat_short(r,k) = (r>>4)*8192 + (k>>5)*512 + ((k>>3)&3)*128 + (r&15)*8 + (k&7)
// Packed-V (attn PV A-operand), per bh (65536 shorts), s-tile of 64:
//   V[ch][s] at stile*4096 + nj*1024 + kk*512 + g*128 + li*8 + e
//   where ch = nj*16 + li, s = kk*32 + g*8 + e.

// ---------------- Fused GroupNorm: one block per (b,g); writes hnT packed.
__global__ __launch_bounds__(256) void k_gn_fused(const float* __restrict__ x,
                                                  const float* __restrict__ nw,
                                                  const float* __restrict__ nb,
                                                  unsigned short* __restrict__ hnT) {
  int bg = blockIdx.x;
  int b = bg >> 5, g = bg & 31;
  size_t base = (size_t)(b * 512 + g * 16) * 1024;
  const float4* p = reinterpret_cast<const float4*>(x + base);
  float s = 0.f, ss = 0.f;
#pragma unroll
  for (int i = 0; i < 16; ++i) {
    float4 v = p[threadIdx.x + i * 256];
    s += v.x + v.y + v.z + v.w;
    ss += v.x * v.x + v.y * v.y + v.z * v.z + v.w * v.w;
  }
#pragma unroll
  for (int off = 1; off < 64; off <<= 1) {
    s += __shfl_xor(s, off, 64);
    ss += __shfl_xor(ss, off, 64);
  }
  __shared__ float rbuf[4][2];
  __shared__ float stat[2];
  int wave = threadIdx.x >> 6;
  if ((threadIdx.x & 63) == 0) { rbuf[wave][0] = s; rbuf[wave][1] = ss; }
  __syncthreads();
  if (threadIdx.x == 0) {
    float S = 0.f, SS = 0.f;
    for (int i = 0; i < 4; ++i) { S += rbuf[i][0]; SS += rbuf[i][1]; }
    float m = S * (1.f / 16384.f);
    float var = SS * (1.f / 16384.f) - m * m;
    stat[0] = m;
    stat[1] = rsqrtf(var + 1e-5f);
  }
  __syncthreads();
  float mu = stat[0], rinv = stat[1];

  int tid = threadIdx.x;
#pragma unroll
  for (int q = 0; q < 2; ++q) {
    int c0 = g * 16 + q * 8;
    float a[8], bb[8];
#pragma unroll
    for (int cc = 0; cc < 8; ++cc) {
      a[cc] = rinv * nw[c0 + cc];
      bb[cc] = nb[c0 + cc] - mu * a[cc];
    }
    size_t cpart = (size_t)(c0 >> 5) * 512 + (size_t)((c0 >> 3) & 3) * 128;
#pragma unroll
    for (int it = 0; it < 4; ++it) {
      int t = it * 256 + tid;
      u16x8 o;
#pragma unroll
      for (int cc = 0; cc < 8; ++cc) {
        float v = x[base + (size_t)(q * 8 + cc) * 1024 + t];
        o[cc] = f2bf(v * a[cc] + bb[cc]);
      }
      size_t dst = (size_t)b * 524288 + (size_t)(t >> 4) * 8192 + cpart + (t & 15) * 8;
      *reinterpret_cast<u16x8*>(hnT + dst) = o;
    }
  }
}

// ---------------- merged weight prep: qkv packed-frag + proj row-major bf16
__global__ void k_prep_w(const float* __restrict__ qkv_w, const float* __restrict__ proj_w,
                         unsigned short* __restrict__ wqb, unsigned short* __restrict__ wpb) {
  int i = blockIdx.x * blockDim.x + threadIdx.x;
  if (i < 98304) {
    int r = i >> 6, k8 = i & 63;
    const float4* s = reinterpret_cast<const float4*>(qkv_w + (size_t)r * 512 + k8 * 8);
    float4 v0 = s[0], v1 = s[1];
    u16x8 o;
    o[0] = f2bf(v0.x); o[1] = f2bf(v0.y); o[2] = f2bf(v0.z); o[3] = f2bf(v0.w);
    o[4] = f2bf(v1.x); o[5] = f2bf(v1.y); o[6] = f2bf(v1.z); o[7] = f2bf(v1.w);
    size_t d = (size_t)(r >> 4) * 8192 + (size_t)(k8 >> 2) * 512 + (k8 & 3) * 128 + (r & 15) * 8;
    *reinterpret_cast<u16x8*>(wqb + d) = o;
  } else {
    int j = i - 98304;  // j < 65536
    float4 v = reinterpret_cast<const float4*>(proj_w)[j];
    u16x4 o;
    o[0] = f2bf(v.x); o[1] = f2bf(v.y); o[2] = f2bf(v.z); o[3] = f2bf(v.w);
    reinterpret_cast<u16x4*>(wpb)[j] = o;
  }
}

#define MFMAS(AF, BF)                                                                     \
  do {                                                                                    \
    _Pragma("unroll") for (int mi = 0; mi < 4; ++mi)                                      \
      _Pragma("unroll") for (int ni = 0; ni < 4; ++ni)                                    \
        acc[mi][ni] =                                                                     \
            __builtin_amdgcn_mfma_f32_16x16x32_bf16(AF[mi], BF[ni], acc[mi][ni], 0, 0, 0);\
  } while (0)

#define LOADT(DA, DB, kb)                                                                 \
  do {                                                                                    \
    _Pragma("unroll") for (int mi = 0; mi < 4; ++mi)                                      \
      DA[mi] = *reinterpret_cast<const bf16x8*>(pA + (size_t)mi * 8192 + (kb) * 512);     \
    _Pragma("unroll") for (int ni = 0; ni < 4; ++ni)                                      \
      DB[ni] = *reinterpret_cast<const bf16x8*>(pB + (size_t)ni * 8192 + (kb) * 512);     \
  } while (0)

// ---------------- QKV GEMM: LDS-free packed-operand register streaming.
// (256,1): ~192-VGPR true register double-buffer (R11 showed (256,2) serialized at 92).
__global__ __launch_bounds__(256, 1) void k_qkv_gemm(
    const unsigned short* __restrict__ hnT, const unsigned short* __restrict__ wq,
    const float* __restrict__ qkv_b, unsigned short* __restrict__ Q,
    unsigned short* __restrict__ Kq, unsigned short* __restrict__ Vq) {
  int tid = threadIdx.x;
  int lane = tid & 63, wave = tid >> 6;
  int wm = wave >> 1, wn = wave & 1;
  int g = lane >> 4, li = lane & 15;

  int wg = blockIdx.x;
  int lin = (wg & 7) * 192 + (wg >> 3);
  int bx = lin % 12;
  int tmp = lin / 12;
  int by = tmp & 7;
  int b = tmp >> 3;
  int mbase = by * 128;  // t
  int nbase = bx * 128;  // o

  const unsigned short* pA =
      hnT + (size_t)b * 524288 + (size_t)((mbase + wm * 64) >> 4) * 8192 + lane * 8;
  const unsigned short* pB = wq + (size_t)((nbase + wn * 64) >> 4) * 8192 + lane * 8;

  f32x4 zero = {0.f, 0.f, 0.f, 0.f};
  f32x4 acc[4][4];
#pragma unroll
  for (int mi = 0; mi < 4; ++mi)
#pragma unroll
    for (int ni = 0; ni < 4; ++ni) acc[mi][ni] = zero;

  bf16x8 a0[4], b0[4], a1[4], b1[4];
  LOADT(a0, b0, 0);
#pragma unroll
  for (int kb = 0; kb < 16; kb += 2) {
    if (kb + 1 < 16) LOADT(a1, b1, kb + 1);
    MFMAS(a0, b0);
    if (kb + 2 < 16) LOADT(a0, b0, kb + 2);
    MFMAS(a1, b1);
  }

  // per-side scale: sqrt( (1/sqrt(ch)) * log2(e) ) -> QK^T scores in log2 domain
  const float SCALE = 0.42466090143f;
#pragma unroll
  for (int ni = 0; ni < 4; ++ni) {
    int o = nbase + wn * 64 + ni * 16 + li;
    int h = o / 192;
    int j = o - h * 192;
    int bh = b * 8 + h;
    float bias = qkv_b[o];
#pragma unroll
    for (int mi = 0; mi < 4; ++mi) {
      int t0 = mbase + wm * 64 + mi * 16 + g * 4;
      f32x4 v = acc[mi][ni];
      if (j < 64) {
#pragma unroll
        for (int r = 0; r < 4; ++r)
          Q[((size_t)bh * 1024 + t0 + r) * 64 + j] = f2bf((v[r] + bias) * SCALE);
      } else if (j < 128) {
#pragma unroll
        for (int r = 0; r < 4; ++r)
          Kq[((size_t)bh * 1024 + t0 + r) * 64 + (j - 64)] = f2bf((v[r] + bias) * SCALE);
      } else {
        int ch = j - 128;
        int nj = ch >> 4, liv = ch & 15;
        int stile = t0 >> 6, s0 = t0 & 63;
        int kkc = s0 >> 5, gk = (s0 >> 3) & 3, e0 = s0 & 7;
        u16x4 pv;
#pragma unroll
        for (int r = 0; r < 4; ++r) pv[r] = f2bf(v[r] + bias);
        *reinterpret_cast<u16x4*>(Vq + (size_t)bh * 65536 + (size_t)stile * 4096 +
                                  nj * 1024 + kkc * 512 + gk * 128 + liv * 8 + e0) = pv;
      }
    }
  }
}

// ---------------- Flash attention (R10/R13 best config): 4 waves x 32 q-rows, KVBLK=128
// phases, K via LDS dbuf, V reg-streamed from packed layout, register P, setprio.
__global__ __launch_bounds__(256) void k_attn(
    const unsigned short* __restrict__ Q, const unsigned short* __restrict__ K,
    const unsigned short* __restrict__ Vp, unsigned short* __restrict__ aT) {
  __shared__ unsigned short Kls[2][8192];  // [128 rows][64 ch], XOR-swizzled
  int tid = threadIdx.x;
  int lane = tid & 63, w = tid >> 6;
  int g = lane >> 4, li = lane & 15;

  int wg = blockIdx.x;
  int lin = (wg & 7) * 128 + (wg >> 3);
  int qt = lin & 7;  // q-tile fastest: same-XCD consecutive blocks share K/V(bh)
  int bh = lin >> 3;
  int tq0 = qt * 128;
  int b = bh >> 3, h = bh & 7;

  const unsigned short* Kg = K + (size_t)bh * 1024 * 64;
  const unsigned short* Vb = Vp + (size_t)bh * 65536 + lane * 8;

  bf16x8 qf[2][2];
#pragma unroll
  for (int qi = 0; qi < 2; ++qi) {
    int t = tq0 + w * 32 + qi * 16 + li;
    const unsigned short* qp = Q + ((size_t)bh * 1024 + t) * 64 + g * 8;
    qf[qi][0] = *reinterpret_cast<const bf16x8*>(qp);
    qf[qi][1] = *reinterpret_cast<const bf16x8*>(qp + 32);
  }

  // staging: wave w stages rows [w*32, w*32+32) of the 128-row phase tile
  const unsigned short* kg[4];
#pragma unroll
  for (int i = 0; i < 4; ++i) {
    int r = w * 32 + i * 8 + (lane >> 3);
    int hh = (r ^ (r >> 2)) & 7;
    int c = ((lane & 7) ^ hh) * 8;
    kg[i] = Kg + (size_t)r * 64 + c;
  }

  int srowK = ((li >> 2) << 3) | (li & 3);

  f32x4 zero = {0.f, 0.f, 0.f, 0.f};
  f32x4 oacc[2][4];
  f32x4 l_acc[2];
#pragma unroll
  for (int qi = 0; qi < 2; ++qi) {
    l_acc[qi] = zero;
#pragma unroll
    for (int nj = 0; nj < 4; ++nj) oacc[qi][nj] = zero;
  }
  u32x4 onesw = {0x3F803F80u, 0x3F803F80u, 0x3F803F80u, 0x3F803F80u};
  bf16x8 ones = __builtin_bit_cast(bf16x8, onesw);

#define ISSUE(pp, ph)                                                                    \
  do {                                                                                   \
    _Pragma("unroll") for (int i = 0; i < 4; ++i)                                        \
        __builtin_amdgcn_global_load_lds((gconst_void*)(kg[i] + (size_t)(ph) * 8192),    \
                                         (lds_void*)&Kls[pp][w * 2048 + i * 512], 16, 0, \
                                         0);                                             \
  } while (0)

  ISSUE(0, 0);
  for (int ph = 0; ph < 8; ++ph) {
    asm volatile("s_waitcnt vmcnt(0) lgkmcnt(0)" ::: "memory");
    __builtin_amdgcn_s_barrier();
    asm volatile("" ::: "memory");
    if (ph < 7) ISSUE((ph + 1) & 1, ph + 1);

#pragma unroll
    for (int st = 0; st < 2; ++st) {
      const unsigned short* kbase = &Kls[ph & 1][st * 4096];
      const unsigned short* vt = Vb + (size_t)(ph * 2 + st) * 4096;

      // first half of V fragments (nj = 0,1) — latency hides under QK^T+softmax
      bf16x8 vf0[4];
#pragma unroll
      for (int i = 0; i < 4; ++i) vf0[i] = *reinterpret_cast<const bf16x8*>(vt + i * 512);

      // QK^T with permuted s-rows; lane holds S[s=kk*32+g*8+e][q=li]
      f32x4 sacc[2][4];
      __builtin_amdgcn_s_setprio(1);
#pragma unroll
      for (int ni = 0; ni < 4; ++ni) {
        int rK = ((ni >> 1) << 5) + ((ni & 1) << 2) + srowK;
        int hs = ((rK ^ (rK >> 2)) & 7) << 4;
        int off0 = ((g << 4)) ^ hs;
        int off1 = (64 + (g << 4)) ^ hs;
        bf16x8 kf0 = *reinterpret_cast<const bf16x8*>(&kbase[rK * 64 + (off0 >> 1)]);
        bf16x8 kf1 = *reinterpret_cast<const bf16x8*>(&kbase[rK * 64 + (off1 >> 1)]);
#pragma unroll
        for (int qi = 0; qi < 2; ++qi) {
          f32x4 s0 = __builtin_amdgcn_mfma_f32_16x16x32_bf16(kf0, qf[qi][0], zero, 0, 0, 0);
          sacc[qi][ni] = __builtin_amdgcn_mfma_f32_16x16x32_bf16(kf1, qf[qi][1], s0, 0, 0, 0);
        }
      }
      __builtin_amdgcn_s_setprio(0);

      // softmax: exp2 directly (log2-domain scores), pack P, l via ones-MFMA
      bf16x8 pfrag[2][2];
#pragma unroll
      for (int qi = 0; qi < 2; ++qi) {
#pragma unroll
        for (int ni = 0; ni < 4; ++ni)
#pragma unroll
          for (int r = 0; r < 4; ++r) sacc[qi][ni][r] = exp2_fast(sacc[qi][ni][r]);
#pragma unroll
        for (int kk = 0; kk < 2; ++kk) {
          u32x4 pw;
          pw[0] = cvt_pk_bf16(sacc[qi][2 * kk][0], sacc[qi][2 * kk][1]);
          pw[1] = cvt_pk_bf16(sacc[qi][2 * kk][2], sacc[qi][2 * kk][3]);
          pw[2] = cvt_pk_bf16(sacc[qi][2 * kk + 1][0], sacc[qi][2 * kk + 1][1]);
          pw[3] = cvt_pk_bf16(sacc[qi][2 * kk + 1][2], sacc[qi][2 * kk + 1][3]);
          pfrag[qi][kk] = __builtin_bit_cast(bf16x8, pw);
        }
        l_acc[qi] = __builtin_amdgcn_mfma_f32_16x16x32_bf16(ones, pfrag[qi][0], l_acc[qi], 0, 0, 0);
        l_acc[qi] = __builtin_amdgcn_mfma_f32_16x16x32_bf16(ones, pfrag[qi][1], l_acc[qi], 0, 0, 0);
      }

      // second half of V fragments (nj = 2,3)
      bf16x8 vf1[4];
#pragma unroll
      for (int i = 0; i < 4; ++i)
        vf1[i] = *reinterpret_cast<const bf16x8*>(vt + (4 + i) * 512);

      // PV: oacc[qi][nj] += V[ch][s] * P
      __builtin_amdgcn_s_setprio(1);
#pragma unroll
      for (int nj = 0; nj < 2; ++nj)
#pragma unroll
        for (int qi = 0; qi < 2; ++qi) {
          oacc[qi][nj] = __builtin_amdgcn_mfma_f32_16x16x32_bf16(vf0[nj * 2 + 0], pfrag[qi][0], oacc[qi][nj], 0, 0, 0);
          oacc[qi][nj] = __builtin_amdgcn_mfma_f32_16x16x32_bf16(vf0[nj * 2 + 1], pfrag[qi][1], oacc[qi][nj], 0, 0, 0);
        }
#pragma unroll
      for (int nj = 2; nj < 4; ++nj)
#pragma unroll
        for (int qi = 0; qi < 2; ++qi) {
          oacc[qi][nj] = __builtin_amdgcn_mfma_f32_16x16x32_bf16(vf1[(nj - 2) * 2 + 0], pfrag[qi][0], oacc[qi][nj], 0, 0, 0);
          oacc[qi][nj] = __builtin_amdgcn_mfma_f32_16x16x32_bf16(vf1[(nj - 2) * 2 + 1], pfrag[qi][1], oacc[qi][nj], 0, 0, 0);
        }
      __builtin_amdgcn_s_setprio(0);
    }
  }
#undef ISSUE

#pragma unroll
  for (int qi = 0; qi < 2; ++qi) {
    float inv = rcp_fast(l_acc[qi][0]);
    int t = tq0 + w * 32 + qi * 16 + li;
#pragma unroll
    for (int nj = 0; nj < 4; ++nj) {
      u32x2 ov;
      ov[0] = cvt_pk_bf16(oacc[qi][nj][0] * inv, oacc[qi][nj][1] * inv);
      ov[1] = cvt_pk_bf16(oacc[qi][nj][2] * inv, oacc[qi][nj][3] * inv);
      *reinterpret_cast<u32x2*>(aT + ((size_t)b * 1024 + t) * 512 + h * 64 + nj * 16 + g * 4) = ov;
    }
  }
}

// ---------------- proj GEMM + bias + residual: LDS 2-buffer depth-1 pipeline
__global__ __launch_bounds__(256) void k_proj_gemm(
    const unsigned short* __restrict__ aT, const unsigned short* __restrict__ wp,
    const float* __restrict__ proj_b, const float* __restrict__ x,
    float* __restrict__ out) {
  __shared__ unsigned short As[2][4096];
  __shared__ unsigned short Bs[2][4096];
  int tid = threadIdx.x;
  int lane = tid & 63, wave = tid >> 6;
  int wm = wave >> 1, wn = wave & 1;
  int g = lane >> 4, li = lane & 15;

  int wg = blockIdx.x;
  int lin = (wg & 7) * 64 + (wg >> 3);
  int bx = lin & 7;
  int tmp = lin >> 3;
  int by = tmp & 3;
  int b = tmp >> 2;
  int mbase = by * 128;  // o
  int nbase = bx * 128;  // t

  const unsigned short* Ag = wp + (size_t)mbase * 512;
  const unsigned short* Bg = aT + (size_t)b * 1024 * 512 + (size_t)nbase * 512;

  int kq = (lane & 3) ^ ((lane >> 3) & 3);
  int rst = wave * 32 + (lane >> 2);
  const char* pA0 = (const char*)Ag + (size_t)rst * 1024 + kq * 16;
  const char* pA1 = pA0 + 16 * 1024;
  const char* pB0 = (const char*)Bg + (size_t)rst * 1024 + kq * 16;
  const char* pB1 = pB0 + 16 * 1024;
  int ldsA0 = wave * 1024, ldsA1 = wave * 1024 + 512;

  int voff = 32 * li + 8 * (g ^ ((li >> 1) & 3));

  f32x4 zero = {0.f, 0.f, 0.f, 0.f};
  f32x4 acc[4][4];
#pragma unroll
  for (int mi = 0; mi < 4; ++mi)
#pragma unroll
    for (int ni = 0; ni < 4; ++ni) acc[mi][ni] = zero;

#define GISSUE(k0, buf)                                                                  \
  do {                                                                                   \
    __builtin_amdgcn_global_load_lds((gconst_void*)(pA0 + (k0) * 2),                     \
                                     (lds_void*)&As[buf][ldsA0], 16, 0, 0);              \
    __builtin_amdgcn_global_load_lds((gconst_void*)(pA1 + (k0) * 2),                     \
                                     (lds_void*)&As[buf][ldsA1], 16, 0, 0);              \
    __builtin_amdgcn_global_load_lds((gconst_void*)(pB0 + (k0) * 2),                     \
                                     (lds_void*)&Bs[buf][ldsA0], 16, 0, 0);              \
    __builtin_amdgcn_global_load_lds((gconst_void*)(pB1 + (k0) * 2),                     \
                                     (lds_void*)&Bs[buf][ldsA1], 16, 0, 0);              \
  } while (0)

  GISSUE(0, 0);
#pragma unroll
  for (int kk = 0; kk < 16; ++kk) {
    asm volatile("s_waitcnt vmcnt(0)" ::: "memory");
    __builtin_amdgcn_s_barrier();
    asm volatile("" ::: "memory");
    if (kk < 15) GISSUE((kk + 1) * 32, (kk + 1) & 1);
    const int cur = kk & 1;
    bf16x8 af[4], bfr[4];
#pragma unroll
    for (int mi = 0; mi < 4; ++mi)
      af[mi] = *reinterpret_cast<const bf16x8*>(&As[cur][wm * 2048 + mi * 512 + voff]);
#pragma unroll
    for (int ni = 0; ni < 4; ++ni)
      bfr[ni] = *reinterpret_cast<const bf16x8*>(&Bs[cur][wn * 2048 + ni * 512 + voff]);
#pragma unroll
    for (int mi = 0; mi < 4; ++mi)
#pragma unroll
      for (int ni = 0; ni < 4; ++ni)
        acc[mi][ni] = __builtin_amdgcn_mfma_f32_16x16x32_bf16(af[mi], bfr[ni], acc[mi][ni], 0, 0, 0);
  }
#undef GISSUE

#pragma unroll
  for (int mi = 0; mi < 4; ++mi) {
#pragma unroll
    for (int ni = 0; ni < 4; ++ni) {
      int t = nbase + wn * 64 + ni * 16 + li;
      f32x4 v = acc[mi][ni];
#pragma unroll
      for (int r = 0; r < 4; ++r) {
        int o = mbase + wm * 64 + mi * 16 + g * 4 + r;
        size_t idx = ((size_t)(b * 512 + o)) * 1024 + t;
        out[idx] = v[r] + proj_b[o] + x[idx];
      }
    }
  }
}

extern "C" void kernel_launch(void* const* d_in, const int* in_sizes, int n_in,
                              void* d_out, int out_size, void* d_ws, size_t ws_size,
                              hipStream_t stream) {
  (void)in_sizes; (void)n_in; (void)out_size; (void)ws_size;
  const float* x = (const float*)d_in[0];
  const float* norm_w = (const float*)d_in[1];
  const float* norm_b = (const float*)d_in[2];
  const float* qkv_w = (const float*)d_in[3];
  const float* qkv_b = (const float*)d_in[4];
  const float* proj_w = (const float*)d_in[5];
  const float* proj_b = (const float*)d_in[6];
  float* out = (float*)d_out;

  char* ws = (char*)d_ws;
  size_t off = 0;
  unsigned short* hnT = (unsigned short*)(ws + off); off += (size_t)16 * 1024 * 512 * 2;  // packed; reused as row-major aT
  unsigned short* wqb = (unsigned short*)(ws + off); off += (size_t)1536 * 512 * 2;
  unsigned short* wpb = (unsigned short*)(ws + off); off += (size_t)512 * 512 * 2;
  unsigned short* Qb = (unsigned short*)(ws + off); off += (size_t)128 * 1024 * 64 * 2;
  unsigned short* Kb = (unsigned short*)(ws + off); off += (size_t)128 * 1024 * 64 * 2;
  unsigned short* Vb = (unsigned short*)(ws + off); off += (size_t)128 * 1024 * 64 * 2;

  k_gn_fused<<<512, TPB, 0, stream>>>(x, norm_w, norm_b, hnT);
  k_prep_w<<<640, TPB, 0, stream>>>(qkv_w, proj_w, wqb, wpb);
  k_qkv_gemm<<<1536, TPB, 0, stream>>>(hnT, wqb, qkv_b, Qb, Kb, Vb);
  k_attn<<<1024, TPB, 0, stream>>>(Qb, Kb, Vb, hnT /* aT, row-major */);
  k_proj_gemm<<<512, TPB, 0, stream>>>(hnT, wpb, proj_b, x, out);
}